// Round 4
// baseline (497.414 us; speedup 1.0000x reference)
//
#include <hip/hip_runtime.h>

// ---------------------------------------------------------------------------
// GAT 2-layer forward on MI355X. Round 4:
//  KEY: exploit linearity — aggregate BEFORE the conv1 projection.
//    x2[dst,h,:] = (sum_e alpha_e^h * x[src_e,:]) @ W1_h^T
//  so h1 [20000,2048] is never materialized; the per-edge gather shrinks from
//  4 KB (h1 row) to 512 B (x row): 492 MB -> 61 MB logical gather traffic.
//  Attention logits come from v = att @ W1 (tiny), a = x @ v^T.
//  conv1 projection becomes a block-diagonal GEMM (per-head 256-col A slice).
//  h2 stored bf16 (halves conv2 gather). Reverted round-3 x4 unroll (lost).
// ---------------------------------------------------------------------------

#define NEG_SLOPE 0.2f

typedef __attribute__((ext_vector_type(8))) short bf16x8;
typedef __attribute__((ext_vector_type(4))) float f32x4;

__device__ __forceinline__ float bf2f(unsigned short u) {
  return __uint_as_float(((unsigned)u) << 16);
}
__device__ __forceinline__ unsigned short f2bf(float f) {
  unsigned u = __float_as_uint(f);
  u += 0x7fffu + ((u >> 16) & 1u);   // round-to-nearest-even
  return (unsigned short)(u >> 16);
}

__device__ __forceinline__ void async_copy16(const void* g, void* l) {
  __builtin_amdgcn_global_load_lds(
      (const __attribute__((address_space(1))) unsigned int*)g,
      (__attribute__((address_space(3))) unsigned int*)l, 16, 0, 0);
}

// ---------------------------------------------------------------------------
// prep: fold W_node/W_col halves + convert all MFMA operands to bf16.
__global__ void prep(const float* __restrict__ Wn, const float* __restrict__ Wc,
                     const float* __restrict__ W1, const float* __restrict__ W2,
                     const float* __restrict__ Wout,
                     const float* __restrict__ cons, const float* __restrict__ cols,
                     unsigned short* __restrict__ Wn_b, unsigned short* __restrict__ Wc_b,
                     unsigned short* __restrict__ W1b, unsigned short* __restrict__ W2b,
                     unsigned short* __restrict__ Woutb,
                     unsigned short* __restrict__ consb, unsigned short* __restrict__ colsb,
                     int n_cons, int n_cols) {
  const int S0 = 256 * 64;
  const int S1 = 256 * 128;
  const int S2 = 2048 * 256;
  const int S3 = 256 * 2048;
  const int S4 = 128 * 256;
  int total = S0 + S1 + S2 + S3 + S4 + n_cons + n_cols;
  for (int idx = blockIdx.x * 256 + threadIdx.x; idx < total; idx += gridDim.x * 256) {
    int i = idx;
    if (i < S0) { int o = i >> 6, j = i & 63;
      Wn_b[i] = f2bf(Wn[o * 128 + j] + Wn[o * 128 + 64 + j]); continue; }
    i -= S0;
    if (i < S1) { int o = i >> 7, j = i & 127;
      Wc_b[i] = f2bf(Wc[o * 256 + j] + Wc[o * 256 + 128 + j]); continue; }
    i -= S1;
    if (i < S2) { W1b[i] = f2bf(W1[i]); continue; }
    i -= S2;
    if (i < S3) { W2b[i] = f2bf(W2[i]); continue; }
    i -= S3;
    if (i < S4) { Woutb[i] = f2bf(Wout[i]); continue; }
    i -= S4;
    if (i < n_cons) { consb[i] = f2bf(cons[i]); continue; }
    i -= n_cons;
    colsb[i] = f2bf(cols[i]);
  }
}

// ---------------------------------------------------------------------------
// v_s1[h,k] = sum_c att_s[h,c] * W1[h*256+c, k]; v_d1 likewise.
// Block h (8 blocks), thread k (256): coalesced row reads of W1.
__global__ __launch_bounds__(256) void att_vec1(const float* __restrict__ W1,
                                                const float* __restrict__ att_s,
                                                const float* __restrict__ att_d,
                                                float* __restrict__ v_s,
                                                float* __restrict__ v_d) {
  int h = blockIdx.x, k = threadIdx.x;
  float s = 0.f, d = 0.f;
  for (int c = 0; c < 256; ++c) {
    float w = W1[(size_t)(h * 256 + c) * 256 + k];
    s += att_s[h * 256 + c] * w;
    d += att_d[h * 256 + c] * w;
  }
  v_s[h * 256 + k] = s;
  v_d[h * 256 + k] = d;
}

// ---------------------------------------------------------------------------
// a_s1[n,h] = xb[n,:] . v_s[h,:]  (thread per node; v in LDS, broadcast reads)
__global__ __launch_bounds__(256) void a1_dots(const unsigned short* __restrict__ xb,
                                               const float* __restrict__ v_s,
                                               const float* __restrict__ v_d,
                                               float* __restrict__ a_s,
                                               float* __restrict__ a_d, int N) {
  __shared__ float vs[2048], vd[2048];
  for (int i = threadIdx.x; i < 2048; i += 256) { vs[i] = v_s[i]; vd[i] = v_d[i]; }
  __syncthreads();
  int n = blockIdx.x * 256 + threadIdx.x;
  if (n >= N) return;
  const unsigned short* row = xb + (size_t)n * 256;
  float s[8] = {}, d[8] = {};
  for (int c = 0; c < 256; c += 8) {
    bf16x8 xv = *(const bf16x8*)(row + c);
    float xf[8];
#pragma unroll
    for (int i = 0; i < 8; ++i) xf[i] = bf2f(((const unsigned short*)&xv)[i]);
#pragma unroll
    for (int h = 0; h < 8; ++h)
#pragma unroll
      for (int i = 0; i < 8; ++i) {
        s[h] += xf[i] * vs[h * 256 + c + i];
        d[h] += xf[i] * vd[h * 256 + c + i];
      }
  }
#pragma unroll
  for (int h = 0; h < 8; ++h) { a_s[n * 8 + h] = s[h]; a_d[n * 8 + h] = d[h]; }
}

// ---------------------------------------------------------------------------
// bf16 MFMA GEMM, B^T layout: C[m,n] = sum_k A[m, koff+k] * W[n,k] (+bias,relu).
// BDIAG: koff = (n0/256)*256 with A row-stride lda (block-diagonal projection).
// Tile 128x128, BK=64. Requires K%64==0, Nout%128==0.
template <bool C_BF16, bool BIAS, bool RELU, bool BDIAG>
__global__ __launch_bounds__(256) void gemm_mfma_bt(const unsigned short* __restrict__ A,
                                                    const unsigned short* __restrict__ W,
                                                    const float* __restrict__ bias,
                                                    void* __restrict__ Cv,
                                                    int M, int K, int Nout, int lda) {
  __shared__ short sA[128 * 64];
  __shared__ short sB[128 * 64];
  float* Cf = (float*)Cv;
  unsigned short* Cb = (unsigned short*)Cv;

  const int tid = threadIdx.x;
  const int lane = tid & 63, w = tid >> 6;
  const int m0 = blockIdx.y * 128, n0 = blockIdx.x * 128;
  const int koff = BDIAG ? (n0 >> 8) << 8 : 0;
  const int wm = (w >> 1) * 64, wn = (w & 1) * 64;
  const int fr = lane & 15;
  const int quad = lane >> 4;

  f32x4 acc[4][4];
#pragma unroll
  for (int i = 0; i < 4; ++i)
#pragma unroll
    for (int j = 0; j < 4; ++j) acc[i][j] = (f32x4){0.f, 0.f, 0.f, 0.f};

  for (int k0 = 0; k0 < K; k0 += 64) {
#pragma unroll
    for (int i = 0; i < 4; ++i) {
      int c = i * 256 + tid;
      int row = c >> 3, kc = c & 7;
      int grow = m0 + row;
      if (grow >= M) grow = M - 1;
      async_copy16(A + (size_t)grow * lda + koff + k0 + kc * 8, &sA[(i * 256 + w * 64) * 8]);
    }
#pragma unroll
    for (int i = 0; i < 4; ++i) {
      int c = i * 256 + tid;
      int row = c >> 3, kc = c & 7;
      async_copy16(W + (size_t)(n0 + row) * K + k0 + kc * 8, &sB[(i * 256 + w * 64) * 8]);
    }
    __syncthreads();

#pragma unroll
    for (int ks = 0; ks < 2; ++ks) {
      bf16x8 af[4], bfr[4];
#pragma unroll
      for (int mi = 0; mi < 4; ++mi)
        af[mi] = *(const bf16x8*)&sA[(wm + mi * 16 + fr) * 64 + ks * 32 + quad * 8];
#pragma unroll
      for (int ni = 0; ni < 4; ++ni)
        bfr[ni] = *(const bf16x8*)&sB[(wn + ni * 16 + fr) * 64 + ks * 32 + quad * 8];
#pragma unroll
      for (int mi = 0; mi < 4; ++mi)
#pragma unroll
        for (int ni = 0; ni < 4; ++ni)
          acc[mi][ni] = __builtin_amdgcn_mfma_f32_16x16x32_bf16(
              af[mi], bfr[ni], acc[mi][ni], 0, 0, 0);
    }
    __syncthreads();
  }

#pragma unroll
  for (int mi = 0; mi < 4; ++mi) {
#pragma unroll
    for (int ni = 0; ni < 4; ++ni) {
      int col = n0 + wn + ni * 16 + fr;
      float bv = BIAS ? bias[col] : 0.f;
      f32x4 v = acc[mi][ni];
#pragma unroll
      for (int r = 0; r < 4; ++r) {
        int row = m0 + wm + mi * 16 + quad * 4 + r;
        if (row < M) {
          float x = v[r] + bv;
          if (RELU) x = fmaxf(x, 0.f);
          size_t o = (size_t)row * Nout + col;
          if (C_BF16) Cb[o] = f2bf(x); else Cf[o] = x;
        }
      }
    }
  }
}

// ---------------------------------------------------------------------------
// conv2 projection GEMM: C[M,256] = A[M,2048] * W[256,2048]^T.
// Tile 32x256 (full Nout; A read once); grid = M/32 blocks.
template <bool C_BF16>
__global__ __launch_bounds__(256) void gemm_mfma_k2048(const unsigned short* __restrict__ A,
                                                       const unsigned short* __restrict__ W,
                                                       void* __restrict__ Cv,
                                                       int M, int K) {
  __shared__ short sA[32 * 64];
  __shared__ short sB[256 * 64];
  float* Cf = (float*)Cv;
  unsigned short* Cb = (unsigned short*)Cv;
  const int tid = threadIdx.x;
  const int lane = tid & 63, w = tid >> 6;
  const int m0 = blockIdx.x * 32;
  const int fr = lane & 15, quad = lane >> 4;

  f32x4 acc[2][4];
#pragma unroll
  for (int i = 0; i < 2; ++i)
#pragma unroll
    for (int j = 0; j < 4; ++j) acc[i][j] = (f32x4){0.f, 0.f, 0.f, 0.f};

  for (int k0 = 0; k0 < K; k0 += 64) {
    {
      int row = tid >> 3, kc = tid & 7;
      int grow = m0 + row;
      if (grow >= M) grow = M - 1;
      async_copy16(A + (size_t)grow * K + k0 + kc * 8, &sA[(w * 64) * 8]);
    }
#pragma unroll
    for (int i = 0; i < 8; ++i) {
      int c = i * 256 + tid;
      int row = c >> 3, kc = c & 7;
      async_copy16(W + (size_t)row * K + k0 + kc * 8, &sB[(i * 256 + w * 64) * 8]);
    }
    __syncthreads();

#pragma unroll
    for (int ks = 0; ks < 2; ++ks) {
      bf16x8 af[2], bfr[4];
#pragma unroll
      for (int mi = 0; mi < 2; ++mi)
        af[mi] = *(const bf16x8*)&sA[(mi * 16 + fr) * 64 + ks * 32 + quad * 8];
#pragma unroll
      for (int ni = 0; ni < 4; ++ni)
        bfr[ni] = *(const bf16x8*)&sB[(w * 64 + ni * 16 + fr) * 64 + ks * 32 + quad * 8];
#pragma unroll
      for (int mi = 0; mi < 2; ++mi)
#pragma unroll
        for (int ni = 0; ni < 4; ++ni)
          acc[mi][ni] = __builtin_amdgcn_mfma_f32_16x16x32_bf16(
              af[mi], bfr[ni], acc[mi][ni], 0, 0, 0);
    }
    __syncthreads();
  }

#pragma unroll
  for (int mi = 0; mi < 2; ++mi)
#pragma unroll
    for (int ni = 0; ni < 4; ++ni) {
      int col = w * 64 + ni * 16 + fr;
      f32x4 v = acc[mi][ni];
#pragma unroll
      for (int r = 0; r < 4; ++r) {
        int row = m0 + mi * 16 + quad * 4 + r;
        if (row < M) {
          size_t o = (size_t)row * 256 + col;
          if (C_BF16) Cb[o] = f2bf(v[r]); else Cf[o] = v[r];
        }
      }
    }
}

// ---------------------------------------------------------------------------
// a_s[n] = dot(h[n,:], att_s[:]) for H=1, bf16 rows. One wave per node.
__global__ __launch_bounds__(256) void att_dots1h(const unsigned short* __restrict__ hv,
                                                  const float* __restrict__ att_s,
                                                  const float* __restrict__ att_d,
                                                  float* __restrict__ a_s,
                                                  float* __restrict__ a_d, int N) {
  int wid = (blockIdx.x * 256 + threadIdx.x) >> 6;
  int lane = threadIdx.x & 63;
  if (wid >= N) return;
  int c = lane * 4;
  const unsigned short* row = hv + (size_t)wid * 256;
  ushort4 r = *(const ushort4*)(row + c);
  float v0 = bf2f(r.x), v1 = bf2f(r.y), v2 = bf2f(r.z), v3 = bf2f(r.w);
  float4 sa = *(const float4*)(att_s + c);
  float4 da = *(const float4*)(att_d + c);
  float s1 = v0 * sa.x + v1 * sa.y + v2 * sa.z + v3 * sa.w;
  float s2 = v0 * da.x + v1 * da.y + v2 * da.z + v3 * da.w;
#pragma unroll
  for (int off = 32; off; off >>= 1) {
    s1 += __shfl_down(s1, off);
    s2 += __shfl_down(s2, off);
  }
  if (lane == 0) { a_s[wid] = s1; a_d[wid] = s2; }
}

// ---------------------------------------------------------------------------
// Edge materialization + degree counts (fused). int64/int32 auto-detect.
__global__ void build_count(const void* __restrict__ edges_raw, int E, int N,
                            int* __restrict__ esrc, int* __restrict__ edst,
                            int* __restrict__ cnt1, int* __restrict__ cnt2, int E1) {
  const long long* p64 = (const long long*)edges_raw;
  const int* p32 = (const int*)edges_raw;
  bool is64 = true;
#pragma unroll
  for (int i = 0; i < 8; ++i) {
    long long v = p64[i];
    if (v < 0 || v >= N) is64 = false;
  }
  int idx = blockIdx.x * 256 + threadIdx.x;
  if (idx >= E1) return;
  int s, d;
  if (idx < E) {
    if (is64) { s = (int)p64[idx]; d = (int)p64[E + idx]; }
    else      { s = p32[idx];      d = p32[E + idx]; }
  } else {
    s = d = idx - E;
  }
  esrc[idx] = s;
  edst[idx] = d;
  atomicAdd(&cnt1[d], 1);
  atomicAdd(&cnt2[s], 1);
}

// ---------------------------------------------------------------------------
// Shuffle-based single-block scan: 3 barriers per 1024-chunk.
__device__ __forceinline__ void scan_one(const int* __restrict__ cnt,
                                         int* __restrict__ indptr,
                                         int* __restrict__ cur, int N, int* buf) {
  int t = threadIdx.x, lane = t & 63, w = t >> 6;
  int running = 0;
  for (int base = 0; base < N; base += 1024) {
    int v = (base + t < N) ? cnt[base + t] : 0;
    int incl = v;
#pragma unroll
    for (int off = 1; off < 64; off <<= 1) {
      int y = __shfl_up(incl, off);
      if (lane >= off) incl += y;
    }
    if (lane == 63) buf[w] = incl;
    __syncthreads();
    if (t < 16) {
      int x = buf[t];
#pragma unroll
      for (int off = 1; off < 16; off <<= 1) {
        int y = __shfl_up(x, off);
        if (t >= off) x += y;
      }
      buf[t] = x;
    }
    __syncthreads();
    int woff = w ? buf[w - 1] : 0;
    int tot = buf[15];
    if (base + t < N) {
      int excl = running + woff + incl - v;
      indptr[base + t] = excl;
      cur[base + t] = excl;
    }
    running += tot;
    __syncthreads();
  }
  if (t == 0) indptr[N] = running;
  __syncthreads();
}

__global__ __launch_bounds__(1024) void scan2_kernel(const int* cnt1, int* indptr1, int* cur1,
                                                     const int* cnt2, int* indptr2, int* cur2,
                                                     int N) {
  __shared__ int buf[16];
  scan_one(cnt1, indptr1, cur1, N, buf);
  scan_one(cnt2, indptr2, cur2, N, buf);
}

__global__ void scatter_edges(const int* __restrict__ esrc, const int* __restrict__ edst,
                              int* __restrict__ cur1, int* __restrict__ cur2,
                              int* __restrict__ eidx1, int* __restrict__ eidx2, int E1) {
  int e = blockIdx.x * 256 + threadIdx.x;
  if (e >= E1) return;
  int p1 = atomicAdd(&cur1[edst[e]], 1);
  eidx1[p1] = e;
  int p2 = atomicAdd(&cur2[esrc[e]], 1);
  eidx2[p2] = e;
}

// ---------------------------------------------------------------------------
// conv1 pre-aggregation: agg[dst, h*256+c] = sum_e alpha_e^h * xb[src_e, c].
// One block per dst. Thread t: head = t>>5, channels [(t&31)*8, +8).
__global__ __launch_bounds__(256) void conv1_agg_pre(const unsigned short* __restrict__ xb,
                                                     const float* __restrict__ a_s,
                                                     const float* __restrict__ a_d,
                                                     const int* __restrict__ esrc,
                                                     const int* __restrict__ indptr,
                                                     const int* __restrict__ eidx,
                                                     unsigned short* __restrict__ agg) {
  int dst = blockIdx.x, tid = threadIdx.x;
  int start = indptr[dst];
  int deg = indptr[dst + 1] - start;
  __shared__ float m_sh[8], d_sh[8];
  __shared__ float al_sh[64 * 8];
  __shared__ int src_sh[64];
  int lane = tid & 63, wave = tid >> 6;

  // softmax stats: wave w handles heads w, w+4
  for (int h = wave; h < 8; h += 4) {
    float ad = a_d[dst * 8 + h];
    float mx = -1e30f;
    for (int j = lane; j < deg; j += 64) {
      int e = eidx[start + j];
      float ev = a_s[esrc[e] * 8 + h] + ad;
      ev = ev > 0.f ? ev : NEG_SLOPE * ev;
      mx = fmaxf(mx, ev);
    }
#pragma unroll
    for (int off = 32; off; off >>= 1) mx = fmaxf(mx, __shfl_down(mx, off));
    mx = __shfl(mx, 0);
    float sm = 0.f;
    for (int j = lane; j < deg; j += 64) {
      int e = eidx[start + j];
      float ev = a_s[esrc[e] * 8 + h] + ad;
      ev = ev > 0.f ? ev : NEG_SLOPE * ev;
      sm += __expf(ev - mx);
    }
#pragma unroll
    for (int off = 32; off; off >>= 1) sm += __shfl_down(sm, off);
    if (lane == 0) { m_sh[h] = mx; d_sh[h] = sm + 1e-16f; }
  }
  __syncthreads();

  float acc[8] = {0.f, 0.f, 0.f, 0.f, 0.f, 0.f, 0.f, 0.f};
  const int h = tid >> 5, c0 = (tid & 31) * 8;
  for (int base = 0; base < deg; base += 64) {
    int cnt = min(64, deg - base);
    for (int t = tid; t < cnt * 8; t += 256) {
      int j = t >> 3, hh = t & 7;
      int e = eidx[start + base + j];
      int s = esrc[e];
      if (hh == 0) src_sh[j] = s;
      float ev = a_s[s * 8 + hh] + a_d[dst * 8 + hh];
      ev = ev > 0.f ? ev : NEG_SLOPE * ev;
      al_sh[j * 8 + hh] = __expf(ev - m_sh[hh]) / d_sh[hh];
    }
    __syncthreads();
    for (int j = 0; j < cnt; ++j) {
      float al = al_sh[j * 8 + h];
      bf16x8 xv = *(const bf16x8*)(xb + (size_t)src_sh[j] * 256 + c0);
      const unsigned short* xp = (const unsigned short*)&xv;
#pragma unroll
      for (int i = 0; i < 8; ++i) acc[i] += al * bf2f(xp[i]);
    }
    __syncthreads();
  }

  unsigned short outv[8];
#pragma unroll
  for (int i = 0; i < 8; ++i) outv[i] = f2bf(acc[i]);
  *((float4*)(agg + (size_t)dst * 2048 + h * 256 + c0)) = *((const float4*)outv);
}

// ---------------------------------------------------------------------------
// conv2: 1 head; gathers bf16 h2 rows (512 B/edge); writes x3 bf16.
__global__ __launch_bounds__(256) void conv2_agg(const unsigned short* __restrict__ h2,
                                                 const float* __restrict__ a_s,
                                                 const float* __restrict__ a_d,
                                                 const int* __restrict__ other,
                                                 const int* __restrict__ indptr,
                                                 const int* __restrict__ eidx,
                                                 const float* __restrict__ b2,
                                                 unsigned short* __restrict__ x3) {
  int dst = blockIdx.x, tid = threadIdx.x;
  int start = indptr[dst];
  int deg = indptr[dst + 1] - start;
  __shared__ float md[2];
  __shared__ float al_sh[64];
  __shared__ int src_sh[64];
  int lane = tid & 63, wave = tid >> 6;

  if (wave == 0) {
    float ad = a_d[dst];
    float mx = -1e30f;
    for (int j = lane; j < deg; j += 64) {
      float ev = a_s[other[eidx[start + j]]] + ad;
      ev = ev > 0.f ? ev : NEG_SLOPE * ev;
      mx = fmaxf(mx, ev);
    }
#pragma unroll
    for (int off = 32; off; off >>= 1) mx = fmaxf(mx, __shfl_down(mx, off));
    mx = __shfl(mx, 0);
    float sm = 0.f;
    for (int j = lane; j < deg; j += 64) {
      float ev = a_s[other[eidx[start + j]]] + ad;
      ev = ev > 0.f ? ev : NEG_SLOPE * ev;
      sm += __expf(ev - mx);
    }
#pragma unroll
    for (int off = 32; off; off >>= 1) sm += __shfl_down(sm, off);
    if (lane == 0) { md[0] = mx; md[1] = sm + 1e-16f; }
  }
  __syncthreads();
  float mx = md[0], dn = md[1];
  float acc = 0.f;
  for (int base = 0; base < deg; base += 64) {
    int cnt = min(64, deg - base);
    if (tid < cnt) {
      int s = other[eidx[start + base + tid]];
      float ev = a_s[s] + a_d[dst];
      ev = ev > 0.f ? ev : NEG_SLOPE * ev;
      al_sh[tid] = __expf(ev - mx) / dn;
      src_sh[tid] = s;
    }
    __syncthreads();
    for (int j = 0; j < cnt; ++j)
      acc += al_sh[j] * bf2f(h2[(size_t)src_sh[j] * 256 + tid]);
    __syncthreads();
  }
  float v = acc + b2[tid];
  x3[(size_t)dst * 256 + tid] = f2bf(fmaxf(v, 0.f));
}

// ---------------------------------------------------------------------------
extern "C" void kernel_launch(void* const* d_in, const int* in_sizes, int n_in,
                              void* d_out, int out_size, void* d_ws, size_t ws_size,
                              hipStream_t stream) {
  (void)n_in; (void)out_size; (void)ws_size;
  const float* constraints = (const float*)d_in[0];
  const float* columns     = (const float*)d_in[1];
  const void*  edges       = d_in[2];
  const float* W_node = (const float*)d_in[3];
  const float* b_node = (const float*)d_in[4];
  const float* W_col  = (const float*)d_in[5];
  const float* b_col  = (const float*)d_in[6];
  const float* W1       = (const float*)d_in[7];
  const float* att_src1 = (const float*)d_in[8];
  const float* att_dst1 = (const float*)d_in[9];
  const float* b1       = (const float*)d_in[10];
  const float* W2       = (const float*)d_in[11];
  const float* att_src2 = (const float*)d_in[12];
  const float* att_dst2 = (const float*)d_in[13];
  const float* b2       = (const float*)d_in[14];
  const float* W_out    = (const float*)d_in[15];
  const float* b_out    = (const float*)d_in[16];

  const int Nc   = in_sizes[0] / 64;
  const int Ncol = in_sizes[1] / 128;
  const int E    = in_sizes[2] / 2;
  const int N    = Nc + Ncol;
  const int E1   = E + N;

  char* p = (char*)d_ws;
  size_t off = 0;
  auto alloc = [&](size_t nbytes) -> void* {
    void* r = p + off;
    off = (off + nbytes + 255) & ~(size_t)255;
    return r;
  };
  unsigned short* Wn_b  = (unsigned short*)alloc(2ull * 256 * 64);
  unsigned short* Wc_b  = (unsigned short*)alloc(2ull * 256 * 128);
  unsigned short* W1b   = (unsigned short*)alloc(2ull * 2048 * 256);
  unsigned short* W2b   = (unsigned short*)alloc(2ull * 256 * 2048);
  unsigned short* Woutb = (unsigned short*)alloc(2ull * 128 * 256);
  unsigned short* consb = (unsigned short*)alloc(2ull * (size_t)Nc * 64);
  unsigned short* colsb = (unsigned short*)alloc(2ull * (size_t)Ncol * 128);
  unsigned short* xb    = (unsigned short*)alloc(2ull * (size_t)N * 256);
  float* v_s1 = (float*)alloc(sizeof(float) * 8 * 256);
  float* v_d1 = (float*)alloc(sizeof(float) * 8 * 256);
  float* a_s1 = (float*)alloc(sizeof(float) * (size_t)N * 8);
  float* a_d1 = (float*)alloc(sizeof(float) * (size_t)N * 8);
  int* esrc = (int*)alloc(4ull * E1);
  int* edst = (int*)alloc(4ull * E1);
  int* cnt1 = (int*)alloc(4ull * 2 * N);
  int* cnt2 = cnt1 + N;
  int* indptr1 = (int*)alloc(4ull * (N + 1));
  int* cur1    = (int*)alloc(4ull * N);
  int* indptr2 = (int*)alloc(4ull * (N + 1));
  int* cur2    = (int*)alloc(4ull * N);
  int* eidx1 = (int*)alloc(4ull * E1);
  int* eidx2 = (int*)alloc(4ull * E1);
  unsigned short* agg = (unsigned short*)alloc(2ull * (size_t)N * 2048);
  unsigned short* x2  = (unsigned short*)alloc(2ull * (size_t)N * 2048);
  unsigned short* h2b = (unsigned short*)alloc(2ull * (size_t)N * 256);
  float* a_s2 = (float*)alloc(sizeof(float) * (size_t)N);
  float* a_d2 = (float*)alloc(sizeof(float) * (size_t)N);
  unsigned short* x3 = (unsigned short*)alloc(2ull * (size_t)N * 256);

  hipMemsetAsync(cnt1, 0, 4ull * 2 * N, stream);
  prep<<<1024, 256, 0, stream>>>(W_node, W_col, W1, W2, W_out, constraints, columns,
                                 Wn_b, Wc_b, W1b, W2b, Woutb, consb, colsb,
                                 Nc * 64, Ncol * 128);
  att_vec1<<<8, 256, 0, stream>>>(W1, att_src1, att_dst1, v_s1, v_d1);

  // encoder (MFMA, bf16 -> xb)
  gemm_mfma_bt<true, true, true, false><<<dim3(2, (Nc + 127) / 128), 256, 0, stream>>>(
      consb, Wn_b, b_node, xb, Nc, 64, 256, 64);
  gemm_mfma_bt<true, true, true, false><<<dim3(2, (Ncol + 127) / 128), 256, 0, stream>>>(
      colsb, Wc_b, b_col, xb + (size_t)Nc * 256, Ncol, 128, 256, 128);

  // attention logits for conv1 (from xb, no h1 needed)
  a1_dots<<<(N + 255) / 256, 256, 0, stream>>>(xb, v_s1, v_d1, a_s1, a_d1, N);

  // graph CSR (both directions)
  build_count<<<(E1 + 255) / 256, 256, 0, stream>>>(edges, E, N, esrc, edst, cnt1, cnt2, E1);
  scan2_kernel<<<1, 1024, 0, stream>>>(cnt1, indptr1, cur1, cnt2, indptr2, cur2, N);
  scatter_edges<<<(E1 + 255) / 256, 256, 0, stream>>>(esrc, edst, cur1, cur2, eidx1, eidx2, E1);

  // conv1: aggregate in input space, then block-diagonal projection -> x2
  conv1_agg_pre<<<N, 256, 0, stream>>>(xb, a_s1, a_d1, esrc, indptr1, eidx1, agg);
  gemm_mfma_bt<true, true, true, true><<<dim3(16, (N + 127) / 128), 256, 0, stream>>>(
      agg, W1b, b1, x2, N, 256, 2048, 2048);

  // conv2: project (bf16 h2), logits, aggregate
  gemm_mfma_k2048<true><<<(N + 31) / 32, 256, 0, stream>>>(x2, W2b, h2b, N, 2048);
  att_dots1h<<<(N + 3) / 4, 256, 0, stream>>>(h2b, att_src2, att_dst2, a_s2, a_d2, N);
  conv2_agg<<<N, 256, 0, stream>>>(h2b, a_s2, a_d2, edst, indptr2, eidx2, b2, x3);

  // output projection (rows Nc..N) -> d_out f32
  gemm_mfma_bt<false, true, false, false><<<dim3(1, (Ncol + 127) / 128), 256, 0, stream>>>(
      x3 + (size_t)Nc * 256, Woutb, b_out, (float*)d_out, Ncol, 256, 128, 256);
}

// Round 5
// 465.225 us; speedup vs baseline: 1.0692x; 1.0692x over previous
//
#include <hip/hip_runtime.h>

// ---------------------------------------------------------------------------
// GAT 2-layer forward on MI355X. Round 5:
//  - wave-per-dst aggregation (4 dsts/block, no block barriers): avg degree is
//    only 6, so per-block overhead/latency dominated the old 1-block-per-dst
//    kernels. Online (flash-style) softmax in registers, single pass.
//  - CSR stores neighbor node-ids directly (no eidx indirection): dependent
//    load chain 3 -> 2.
//  - keeps round-4 algebra: aggregate in 256-dim input space, block-diagonal
//    conv1 projection, bf16 intermediates everywhere.
// ---------------------------------------------------------------------------

#define NEG_SLOPE 0.2f

typedef __attribute__((ext_vector_type(8))) short bf16x8;
typedef __attribute__((ext_vector_type(4))) float f32x4;

__device__ __forceinline__ float bf2f(unsigned short u) {
  return __uint_as_float(((unsigned)u) << 16);
}
__device__ __forceinline__ unsigned short f2bf(float f) {
  unsigned u = __float_as_uint(f);
  u += 0x7fffu + ((u >> 16) & 1u);   // round-to-nearest-even
  return (unsigned short)(u >> 16);
}

__device__ __forceinline__ void async_copy16(const void* g, void* l) {
  __builtin_amdgcn_global_load_lds(
      (const __attribute__((address_space(1))) unsigned int*)g,
      (__attribute__((address_space(3))) unsigned int*)l, 16, 0, 0);
}

// ---------------------------------------------------------------------------
// prep: fold W_node/W_col halves + convert all MFMA operands to bf16.
__global__ void prep(const float* __restrict__ Wn, const float* __restrict__ Wc,
                     const float* __restrict__ W1, const float* __restrict__ W2,
                     const float* __restrict__ Wout,
                     const float* __restrict__ cons, const float* __restrict__ cols,
                     unsigned short* __restrict__ Wn_b, unsigned short* __restrict__ Wc_b,
                     unsigned short* __restrict__ W1b, unsigned short* __restrict__ W2b,
                     unsigned short* __restrict__ Woutb,
                     unsigned short* __restrict__ consb, unsigned short* __restrict__ colsb,
                     int n_cons, int n_cols) {
  const int S0 = 256 * 64;
  const int S1 = 256 * 128;
  const int S2 = 2048 * 256;
  const int S3 = 256 * 2048;
  const int S4 = 128 * 256;
  int total = S0 + S1 + S2 + S3 + S4 + n_cons + n_cols;
  for (int idx = blockIdx.x * 256 + threadIdx.x; idx < total; idx += gridDim.x * 256) {
    int i = idx;
    if (i < S0) { int o = i >> 6, j = i & 63;
      Wn_b[i] = f2bf(Wn[o * 128 + j] + Wn[o * 128 + 64 + j]); continue; }
    i -= S0;
    if (i < S1) { int o = i >> 7, j = i & 127;
      Wc_b[i] = f2bf(Wc[o * 256 + j] + Wc[o * 256 + 128 + j]); continue; }
    i -= S1;
    if (i < S2) { W1b[i] = f2bf(W1[i]); continue; }
    i -= S2;
    if (i < S3) { W2b[i] = f2bf(W2[i]); continue; }
    i -= S3;
    if (i < S4) { Woutb[i] = f2bf(Wout[i]); continue; }
    i -= S4;
    if (i < n_cons) { consb[i] = f2bf(cons[i]); continue; }
    i -= n_cons;
    colsb[i] = f2bf(cols[i]);
  }
}

// ---------------------------------------------------------------------------
// v_s1[h,k] = sum_c att_s[h,c] * W1[h*256+c, k]; v_d1 likewise.
__global__ __launch_bounds__(256) void att_vec1(const float* __restrict__ W1,
                                                const float* __restrict__ att_s,
                                                const float* __restrict__ att_d,
                                                float* __restrict__ v_s,
                                                float* __restrict__ v_d) {
  int h = blockIdx.x, k = threadIdx.x;
  float s = 0.f, d = 0.f;
  for (int c = 0; c < 256; ++c) {
    float w = W1[(size_t)(h * 256 + c) * 256 + k];
    s += att_s[h * 256 + c] * w;
    d += att_d[h * 256 + c] * w;
  }
  v_s[h * 256 + k] = s;
  v_d[h * 256 + k] = d;
}

// ---------------------------------------------------------------------------
// a_s1[n,h] = xb[n,:] . v_s[h,:]  (thread per node; v in LDS, broadcast reads)
__global__ __launch_bounds__(256) void a1_dots(const unsigned short* __restrict__ xb,
                                               const float* __restrict__ v_s,
                                               const float* __restrict__ v_d,
                                               float* __restrict__ a_s,
                                               float* __restrict__ a_d, int N) {
  __shared__ float vs[2048], vd[2048];
  for (int i = threadIdx.x; i < 2048; i += 256) { vs[i] = v_s[i]; vd[i] = v_d[i]; }
  __syncthreads();
  int n = blockIdx.x * 256 + threadIdx.x;
  if (n >= N) return;
  const unsigned short* row = xb + (size_t)n * 256;
  float s[8] = {}, d[8] = {};
  for (int c = 0; c < 256; c += 8) {
    bf16x8 xv = *(const bf16x8*)(row + c);
    float xf[8];
#pragma unroll
    for (int i = 0; i < 8; ++i) xf[i] = bf2f(((const unsigned short*)&xv)[i]);
#pragma unroll
    for (int h = 0; h < 8; ++h)
#pragma unroll
      for (int i = 0; i < 8; ++i) {
        s[h] += xf[i] * vs[h * 256 + c + i];
        d[h] += xf[i] * vd[h * 256 + c + i];
      }
  }
#pragma unroll
  for (int h = 0; h < 8; ++h) { a_s[n * 8 + h] = s[h]; a_d[n * 8 + h] = d[h]; }
}

// ---------------------------------------------------------------------------
// bf16 MFMA GEMM, B^T layout: C[m,n] = sum_k A[m, koff+k] * W[n,k] (+bias,relu).
// BDIAG: koff = (n0/256)*256 with A row-stride lda (block-diagonal projection).
template <bool C_BF16, bool BIAS, bool RELU, bool BDIAG>
__global__ __launch_bounds__(256) void gemm_mfma_bt(const unsigned short* __restrict__ A,
                                                    const unsigned short* __restrict__ W,
                                                    const float* __restrict__ bias,
                                                    void* __restrict__ Cv,
                                                    int M, int K, int Nout, int lda) {
  __shared__ short sA[128 * 64];
  __shared__ short sB[128 * 64];
  float* Cf = (float*)Cv;
  unsigned short* Cb = (unsigned short*)Cv;

  const int tid = threadIdx.x;
  const int lane = tid & 63, w = tid >> 6;
  const int m0 = blockIdx.y * 128, n0 = blockIdx.x * 128;
  const int koff = BDIAG ? (n0 >> 8) << 8 : 0;
  const int wm = (w >> 1) * 64, wn = (w & 1) * 64;
  const int fr = lane & 15;
  const int quad = lane >> 4;

  f32x4 acc[4][4];
#pragma unroll
  for (int i = 0; i < 4; ++i)
#pragma unroll
    for (int j = 0; j < 4; ++j) acc[i][j] = (f32x4){0.f, 0.f, 0.f, 0.f};

  for (int k0 = 0; k0 < K; k0 += 64) {
#pragma unroll
    for (int i = 0; i < 4; ++i) {
      int c = i * 256 + tid;
      int row = c >> 3, kc = c & 7;
      int grow = m0 + row;
      if (grow >= M) grow = M - 1;
      async_copy16(A + (size_t)grow * lda + koff + k0 + kc * 8, &sA[(i * 256 + w * 64) * 8]);
    }
#pragma unroll
    for (int i = 0; i < 4; ++i) {
      int c = i * 256 + tid;
      int row = c >> 3, kc = c & 7;
      async_copy16(W + (size_t)(n0 + row) * K + k0 + kc * 8, &sB[(i * 256 + w * 64) * 8]);
    }
    __syncthreads();

#pragma unroll
    for (int ks = 0; ks < 2; ++ks) {
      bf16x8 af[4], bfr[4];
#pragma unroll
      for (int mi = 0; mi < 4; ++mi)
        af[mi] = *(const bf16x8*)&sA[(wm + mi * 16 + fr) * 64 + ks * 32 + quad * 8];
#pragma unroll
      for (int ni = 0; ni < 4; ++ni)
        bfr[ni] = *(const bf16x8*)&sB[(wn + ni * 16 + fr) * 64 + ks * 32 + quad * 8];
#pragma unroll
      for (int mi = 0; mi < 4; ++mi)
#pragma unroll
        for (int ni = 0; ni < 4; ++ni)
          acc[mi][ni] = __builtin_amdgcn_mfma_f32_16x16x32_bf16(
              af[mi], bfr[ni], acc[mi][ni], 0, 0, 0);
    }
    __syncthreads();
  }

#pragma unroll
  for (int mi = 0; mi < 4; ++mi) {
#pragma unroll
    for (int ni = 0; ni < 4; ++ni) {
      int col = n0 + wn + ni * 16 + fr;
      float bv = BIAS ? bias[col] : 0.f;
      f32x4 v = acc[mi][ni];
#pragma unroll
      for (int r = 0; r < 4; ++r) {
        int row = m0 + wm + mi * 16 + quad * 4 + r;
        if (row < M) {
          float x = v[r] + bv;
          if (RELU) x = fmaxf(x, 0.f);
          size_t o = (size_t)row * Nout + col;
          if (C_BF16) Cb[o] = f2bf(x); else Cf[o] = x;
        }
      }
    }
  }
}

// ---------------------------------------------------------------------------
// conv2 projection GEMM: C[M,256] = A[M,2048] * W[256,2048]^T.
// Tile 32x256 (full Nout; A read once); grid = M/32 blocks.
template <bool C_BF16>
__global__ __launch_bounds__(256) void gemm_mfma_k2048(const unsigned short* __restrict__ A,
                                                       const unsigned short* __restrict__ W,
                                                       void* __restrict__ Cv,
                                                       int M, int K) {
  __shared__ short sA[32 * 64];
  __shared__ short sB[256 * 64];
  float* Cf = (float*)Cv;
  unsigned short* Cb = (unsigned short*)Cv;
  const int tid = threadIdx.x;
  const int lane = tid & 63, w = tid >> 6;
  const int m0 = blockIdx.x * 32;
  const int fr = lane & 15, quad = lane >> 4;

  f32x4 acc[2][4];
#pragma unroll
  for (int i = 0; i < 2; ++i)
#pragma unroll
    for (int j = 0; j < 4; ++j) acc[i][j] = (f32x4){0.f, 0.f, 0.f, 0.f};

  for (int k0 = 0; k0 < K; k0 += 64) {
    {
      int row = tid >> 3, kc = tid & 7;
      int grow = m0 + row;
      if (grow >= M) grow = M - 1;
      async_copy16(A + (size_t)grow * K + k0 + kc * 8, &sA[(w * 64) * 8]);
    }
#pragma unroll
    for (int i = 0; i < 8; ++i) {
      int c = i * 256 + tid;
      int row = c >> 3, kc = c & 7;
      async_copy16(W + (size_t)row * K + k0 + kc * 8, &sB[(i * 256 + w * 64) * 8]);
    }
    __syncthreads();

#pragma unroll
    for (int ks = 0; ks < 2; ++ks) {
      bf16x8 af[2], bfr[4];
#pragma unroll
      for (int mi = 0; mi < 2; ++mi)
        af[mi] = *(const bf16x8*)&sA[(mi * 16 + fr) * 64 + ks * 32 + quad * 8];
#pragma unroll
      for (int ni = 0; ni < 4; ++ni)
        bfr[ni] = *(const bf16x8*)&sB[(w * 64 + ni * 16 + fr) * 64 + ks * 32 + quad * 8];
#pragma unroll
      for (int mi = 0; mi < 2; ++mi)
#pragma unroll
        for (int ni = 0; ni < 4; ++ni)
          acc[mi][ni] = __builtin_amdgcn_mfma_f32_16x16x32_bf16(
              af[mi], bfr[ni], acc[mi][ni], 0, 0, 0);
    }
    __syncthreads();
  }

#pragma unroll
  for (int mi = 0; mi < 2; ++mi)
#pragma unroll
    for (int ni = 0; ni < 4; ++ni) {
      int col = w * 64 + ni * 16 + fr;
      f32x4 v = acc[mi][ni];
#pragma unroll
      for (int r = 0; r < 4; ++r) {
        int row = m0 + mi * 16 + quad * 4 + r;
        if (row < M) {
          size_t o = (size_t)row * 256 + col;
          if (C_BF16) Cb[o] = f2bf(v[r]); else Cf[o] = v[r];
        }
      }
    }
}

// ---------------------------------------------------------------------------
// a_s[n] = dot(h[n,:], att_s[:]) for H=1, bf16 rows. One wave per node.
__global__ __launch_bounds__(256) void att_dots1h(const unsigned short* __restrict__ hv,
                                                  const float* __restrict__ att_s,
                                                  const float* __restrict__ att_d,
                                                  float* __restrict__ a_s,
                                                  float* __restrict__ a_d, int N) {
  int wid = (blockIdx.x * 256 + threadIdx.x) >> 6;
  int lane = threadIdx.x & 63;
  if (wid >= N) return;
  int c = lane * 4;
  const unsigned short* row = hv + (size_t)wid * 256;
  ushort4 r = *(const ushort4*)(row + c);
  float v0 = bf2f(r.x), v1 = bf2f(r.y), v2 = bf2f(r.z), v3 = bf2f(r.w);
  float4 sa = *(const float4*)(att_s + c);
  float4 da = *(const float4*)(att_d + c);
  float s1 = v0 * sa.x + v1 * sa.y + v2 * sa.z + v3 * sa.w;
  float s2 = v0 * da.x + v1 * da.y + v2 * da.z + v3 * da.w;
#pragma unroll
  for (int off = 32; off; off >>= 1) {
    s1 += __shfl_down(s1, off);
    s2 += __shfl_down(s2, off);
  }
  if (lane == 0) { a_s[wid] = s1; a_d[wid] = s2; }
}

// ---------------------------------------------------------------------------
// Edge materialization + degree counts (fused). int64/int32 auto-detect.
__global__ void build_count(const void* __restrict__ edges_raw, int E, int N,
                            int* __restrict__ esrc, int* __restrict__ edst,
                            int* __restrict__ cnt1, int* __restrict__ cnt2, int E1) {
  const long long* p64 = (const long long*)edges_raw;
  const int* p32 = (const int*)edges_raw;
  bool is64 = true;
#pragma unroll
  for (int i = 0; i < 8; ++i) {
    long long v = p64[i];
    if (v < 0 || v >= N) is64 = false;
  }
  int idx = blockIdx.x * 256 + threadIdx.x;
  if (idx >= E1) return;
  int s, d;
  if (idx < E) {
    if (is64) { s = (int)p64[idx]; d = (int)p64[E + idx]; }
    else      { s = p32[idx];      d = p32[E + idx]; }
  } else {
    s = d = idx - E;
  }
  esrc[idx] = s;
  edst[idx] = d;
  atomicAdd(&cnt1[d], 1);
  atomicAdd(&cnt2[s], 1);
}

// ---------------------------------------------------------------------------
// Shuffle-based single-block scan: 3 barriers per 1024-chunk.
__device__ __forceinline__ void scan_one(const int* __restrict__ cnt,
                                         int* __restrict__ indptr,
                                         int* __restrict__ cur, int N, int* buf) {
  int t = threadIdx.x, lane = t & 63, w = t >> 6;
  int running = 0;
  for (int base = 0; base < N; base += 1024) {
    int v = (base + t < N) ? cnt[base + t] : 0;
    int incl = v;
#pragma unroll
    for (int off = 1; off < 64; off <<= 1) {
      int y = __shfl_up(incl, off);
      if (lane >= off) incl += y;
    }
    if (lane == 63) buf[w] = incl;
    __syncthreads();
    if (t < 16) {
      int x = buf[t];
#pragma unroll
      for (int off = 1; off < 16; off <<= 1) {
        int y = __shfl_up(x, off);
        if (t >= off) x += y;
      }
      buf[t] = x;
    }
    __syncthreads();
    int woff = w ? buf[w - 1] : 0;
    int tot = buf[15];
    if (base + t < N) {
      int excl = running + woff + incl - v;
      indptr[base + t] = excl;
      cur[base + t] = excl;
    }
    running += tot;
    __syncthreads();
  }
  if (t == 0) indptr[N] = running;
  __syncthreads();
}

__global__ __launch_bounds__(1024) void scan2_kernel(const int* cnt1, int* indptr1, int* cur1,
                                                     const int* cnt2, int* indptr2, int* cur2,
                                                     int N) {
  __shared__ int buf[16];
  scan_one(cnt1, indptr1, cur1, N, buf);
  scan_one(cnt2, indptr2, cur2, N, buf);
}

// scatter neighbor node-ids directly (removes the eidx indirection):
// dir1 grouped by dst -> neighbor = src; dir2 grouped by src -> neighbor = dst.
__global__ void scatter_edges(const int* __restrict__ esrc, const int* __restrict__ edst,
                              int* __restrict__ cur1, int* __restrict__ cur2,
                              int* __restrict__ nbr1, int* __restrict__ nbr2, int E1) {
  int e = blockIdx.x * 256 + threadIdx.x;
  if (e >= E1) return;
  int s = esrc[e], d = edst[e];
  int p1 = atomicAdd(&cur1[d], 1);
  nbr1[p1] = s;
  int p2 = atomicAdd(&cur2[s], 1);
  nbr2[p2] = d;
}

// ---------------------------------------------------------------------------
// conv1 aggregation, wave-per-dst (4 dst/block, no block barriers).
// agg[dst, h*256+c] = softmax-weighted sum over neighbors of xb[src, c].
// Lane l: head h = l>>3, channels c0 = (l&7)*32 .. +32. Online softmax.
__global__ __launch_bounds__(256) void conv1_agg_wave(const unsigned short* __restrict__ xb,
                                                      const float* __restrict__ a_s,
                                                      const float* __restrict__ a_d,
                                                      const int* __restrict__ indptr,
                                                      const int* __restrict__ nbr,
                                                      unsigned short* __restrict__ agg,
                                                      int N) {
  __shared__ float al_sh[4][64 * 8];
  const int w = threadIdx.x >> 6, lane = threadIdx.x & 63;
  const int dst = blockIdx.x * 4 + w;
  if (dst >= N) return;
  const int start = indptr[dst];
  const int deg = indptr[dst + 1] - start;

  float ad[8];
  *(float4*)&ad[0] = *(const float4*)&a_d[dst * 8];
  *(float4*)&ad[4] = *(const float4*)&a_d[dst * 8 + 4];

  float run_m[8], run_s[8];
#pragma unroll
  for (int hh = 0; hh < 8; ++hh) { run_m[hh] = -1e30f; run_s[hh] = 0.f; }
  float acc[32];
#pragma unroll
  for (int i = 0; i < 32; ++i) acc[i] = 0.f;
  const int h = lane >> 3, c0 = (lane & 7) * 32;

  for (int base = 0; base < deg; base += 64) {
    int cnt = min(64, deg - base);
    float ev[8];
    int s = 0;
    if (lane < cnt) {
      s = nbr[start + base + lane];
      float4 as0 = *(const float4*)&a_s[s * 8];
      float4 as1 = *(const float4*)&a_s[s * 8 + 4];
      float asv[8] = {as0.x, as0.y, as0.z, as0.w, as1.x, as1.y, as1.z, as1.w};
#pragma unroll
      for (int hh = 0; hh < 8; ++hh) {
        float e = asv[hh] + ad[hh];
        ev[hh] = e > 0.f ? e : NEG_SLOPE * e;
      }
    } else {
#pragma unroll
      for (int hh = 0; hh < 8; ++hh) ev[hh] = -1e30f;
    }
    float scale_my = 1.f;
#pragma unroll
    for (int hh = 0; hh < 8; ++hh) {
      float cm = ev[hh];
#pragma unroll
      for (int off = 32; off; off >>= 1) cm = fmaxf(cm, __shfl_xor(cm, off));
      float nm = fmaxf(run_m[hh], cm);
      float sc = __expf(run_m[hh] - nm);
      float e = (lane < cnt) ? __expf(ev[hh] - nm) : 0.f;
      float cs = e;
#pragma unroll
      for (int off = 32; off; off >>= 1) cs += __shfl_xor(cs, off);
      run_s[hh] = run_s[hh] * sc + cs;
      run_m[hh] = nm;
      if (hh == h) scale_my = sc;
      if (lane < cnt) al_sh[w][lane * 8 + hh] = e;
    }
    __builtin_amdgcn_wave_barrier();
#pragma unroll
    for (int i = 0; i < 32; ++i) acc[i] *= scale_my;
    for (int j = 0; j < cnt; ++j) {
      int sj = __shfl(s, j);
      float al = al_sh[w][j * 8 + h];
      const unsigned short* xr = xb + (size_t)sj * 256 + c0;
#pragma unroll
      for (int q = 0; q < 4; ++q) {
        bf16x8 xv = *(const bf16x8*)(xr + q * 8);
        const unsigned short* xp = (const unsigned short*)&xv;
#pragma unroll
        for (int i = 0; i < 8; ++i) acc[q * 8 + i] += al * bf2f(xp[i]);
      }
    }
    __builtin_amdgcn_wave_barrier();
  }

  float inv = 1.f / (run_s[h] + 1e-16f);
  unsigned short* op = agg + (size_t)dst * 2048 + h * 256 + c0;
#pragma unroll
  for (int q = 0; q < 4; ++q) {
    unsigned short outv[8];
#pragma unroll
    for (int i = 0; i < 8; ++i) outv[i] = f2bf(acc[q * 8 + i] * inv);
    *((float4*)(op + q * 8)) = *((const float4*)outv);
  }
}

// ---------------------------------------------------------------------------
// conv2 aggregation, wave-per-dst (4 dst/block), 1 head, pure shuffle.
// Lane l owns channels [4l, 4l+4). 8 B gather per edge per lane.
__global__ __launch_bounds__(256) void conv2_agg_wave(const unsigned short* __restrict__ h2,
                                                      const float* __restrict__ a_s,
                                                      const float* __restrict__ a_d,
                                                      const int* __restrict__ indptr,
                                                      const int* __restrict__ nbr,
                                                      const float* __restrict__ b2,
                                                      unsigned short* __restrict__ x3,
                                                      int N) {
  const int w = threadIdx.x >> 6, lane = threadIdx.x & 63;
  const int dst = blockIdx.x * 4 + w;
  if (dst >= N) return;
  const int start = indptr[dst];
  const int deg = indptr[dst + 1] - start;
  const float ad = a_d[dst];
  float run_m = -1e30f, run_s = 0.f;
  float acc[4] = {0.f, 0.f, 0.f, 0.f};
  const int c0 = lane * 4;

  for (int base = 0; base < deg; base += 64) {
    int cnt = min(64, deg - base);
    float ev = -1e30f;
    int s = 0;
    if (lane < cnt) {
      s = nbr[start + base + lane];
      float e = a_s[s] + ad;
      ev = e > 0.f ? e : NEG_SLOPE * e;
    }
    float cm = ev;
#pragma unroll
    for (int off = 32; off; off >>= 1) cm = fmaxf(cm, __shfl_xor(cm, off));
    float nm = fmaxf(run_m, cm);
    float sc = __expf(run_m - nm);
    float e = (lane < cnt) ? __expf(ev - nm) : 0.f;
    float cs = e;
#pragma unroll
    for (int off = 32; off; off >>= 1) cs += __shfl_xor(cs, off);
    run_s = run_s * sc + cs;
    run_m = nm;
#pragma unroll
    for (int i = 0; i < 4; ++i) acc[i] *= sc;
    for (int j = 0; j < cnt; ++j) {
      int sj = __shfl(s, j);
      float al = __shfl(e, j);
      ushort4 hv = *(const ushort4*)(h2 + (size_t)sj * 256 + c0);
      acc[0] += al * bf2f(hv.x);
      acc[1] += al * bf2f(hv.y);
      acc[2] += al * bf2f(hv.z);
      acc[3] += al * bf2f(hv.w);
    }
  }

  float inv = 1.f / (run_s + 1e-16f);
  float4 bv = *(const float4*)&b2[c0];
  unsigned short ov[4];
  ov[0] = f2bf(fmaxf(acc[0] * inv + bv.x, 0.f));
  ov[1] = f2bf(fmaxf(acc[1] * inv + bv.y, 0.f));
  ov[2] = f2bf(fmaxf(acc[2] * inv + bv.z, 0.f));
  ov[3] = f2bf(fmaxf(acc[3] * inv + bv.w, 0.f));
  *((ushort4*)(x3 + (size_t)dst * 256 + c0)) = *((const ushort4*)ov);
}

// ---------------------------------------------------------------------------
extern "C" void kernel_launch(void* const* d_in, const int* in_sizes, int n_in,
                              void* d_out, int out_size, void* d_ws, size_t ws_size,
                              hipStream_t stream) {
  (void)n_in; (void)out_size; (void)ws_size;
  const float* constraints = (const float*)d_in[0];
  const float* columns     = (const float*)d_in[1];
  const void*  edges       = d_in[2];
  const float* W_node = (const float*)d_in[3];
  const float* b_node = (const float*)d_in[4];
  const float* W_col  = (const float*)d_in[5];
  const float* b_col  = (const float*)d_in[6];
  const float* W1       = (const float*)d_in[7];
  const float* att_src1 = (const float*)d_in[8];
  const float* att_dst1 = (const float*)d_in[9];
  const float* b1       = (const float*)d_in[10];
  const float* W2       = (const float*)d_in[11];
  const float* att_src2 = (const float*)d_in[12];
  const float* att_dst2 = (const float*)d_in[13];
  const float* b2       = (const float*)d_in[14];
  const float* W_out    = (const float*)d_in[15];
  const float* b_out    = (const float*)d_in[16];

  const int Nc   = in_sizes[0] / 64;
  const int Ncol = in_sizes[1] / 128;
  const int E    = in_sizes[2] / 2;
  const int N    = Nc + Ncol;
  const int E1   = E + N;

  char* p = (char*)d_ws;
  size_t off = 0;
  auto alloc = [&](size_t nbytes) -> void* {
    void* r = p + off;
    off = (off + nbytes + 255) & ~(size_t)255;
    return r;
  };
  unsigned short* Wn_b  = (unsigned short*)alloc(2ull * 256 * 64);
  unsigned short* Wc_b  = (unsigned short*)alloc(2ull * 256 * 128);
  unsigned short* W1b   = (unsigned short*)alloc(2ull * 2048 * 256);
  unsigned short* W2b   = (unsigned short*)alloc(2ull * 256 * 2048);
  unsigned short* Woutb = (unsigned short*)alloc(2ull * 128 * 256);
  unsigned short* consb = (unsigned short*)alloc(2ull * (size_t)Nc * 64);
  unsigned short* colsb = (unsigned short*)alloc(2ull * (size_t)Ncol * 128);
  unsigned short* xb    = (unsigned short*)alloc(2ull * (size_t)N * 256);
  float* v_s1 = (float*)alloc(sizeof(float) * 8 * 256);
  float* v_d1 = (float*)alloc(sizeof(float) * 8 * 256);
  float* a_s1 = (float*)alloc(sizeof(float) * (size_t)N * 8);
  float* a_d1 = (float*)alloc(sizeof(float) * (size_t)N * 8);
  int* esrc = (int*)alloc(4ull * E1);
  int* edst = (int*)alloc(4ull * E1);
  int* cnt1 = (int*)alloc(4ull * 2 * N);
  int* cnt2 = cnt1 + N;
  int* indptr1 = (int*)alloc(4ull * (N + 1));
  int* cur1    = (int*)alloc(4ull * N);
  int* indptr2 = (int*)alloc(4ull * (N + 1));
  int* cur2    = (int*)alloc(4ull * N);
  int* nbr1 = (int*)alloc(4ull * E1);
  int* nbr2 = (int*)alloc(4ull * E1);
  unsigned short* agg = (unsigned short*)alloc(2ull * (size_t)N * 2048);
  unsigned short* x2  = (unsigned short*)alloc(2ull * (size_t)N * 2048);
  unsigned short* h2b = (unsigned short*)alloc(2ull * (size_t)N * 256);
  float* a_s2 = (float*)alloc(sizeof(float) * (size_t)N);
  float* a_d2 = (float*)alloc(sizeof(float) * (size_t)N);
  unsigned short* x3 = (unsigned short*)alloc(2ull * (size_t)N * 256);

  hipMemsetAsync(cnt1, 0, 4ull * 2 * N, stream);
  prep<<<1024, 256, 0, stream>>>(W_node, W_col, W1, W2, W_out, constraints, columns,
                                 Wn_b, Wc_b, W1b, W2b, Woutb, consb, colsb,
                                 Nc * 64, Ncol * 128);
  att_vec1<<<8, 256, 0, stream>>>(W1, att_src1, att_dst1, v_s1, v_d1);

  // encoder (MFMA, bf16 -> xb)
  gemm_mfma_bt<true, true, true, false><<<dim3(2, (Nc + 127) / 128), 256, 0, stream>>>(
      consb, Wn_b, b_node, xb, Nc, 64, 256, 64);
  gemm_mfma_bt<true, true, true, false><<<dim3(2, (Ncol + 127) / 128), 256, 0, stream>>>(
      colsb, Wc_b, b_col, xb + (size_t)Nc * 256, Ncol, 128, 256, 128);

  // attention logits for conv1 (from xb, no h1 needed)
  a1_dots<<<(N + 255) / 256, 256, 0, stream>>>(xb, v_s1, v_d1, a_s1, a_d1, N);

  // graph CSR (both directions, neighbor ids stored directly)
  build_count<<<(E1 + 255) / 256, 256, 0, stream>>>(edges, E, N, esrc, edst, cnt1, cnt2, E1);
  scan2_kernel<<<1, 1024, 0, stream>>>(cnt1, indptr1, cur1, cnt2, indptr2, cur2, N);
  scatter_edges<<<(E1 + 255) / 256, 256, 0, stream>>>(esrc, edst, cur1, cur2, nbr1, nbr2, E1);

  // conv1: wave-per-dst aggregation in input space, then block-diag projection
  conv1_agg_wave<<<(N + 3) / 4, 256, 0, stream>>>(xb, a_s1, a_d1, indptr1, nbr1, agg, N);
  gemm_mfma_bt<true, true, true, true><<<dim3(16, (N + 127) / 128), 256, 0, stream>>>(
      agg, W1b, b1, x2, N, 256, 2048, 2048);

  // conv2: project (bf16 h2), logits, wave-per-dst aggregate
  gemm_mfma_k2048<true><<<(N + 31) / 32, 256, 0, stream>>>(x2, W2b, h2b, N, 2048);
  att_dots1h<<<(N + 3) / 4, 256, 0, stream>>>(h2b, att_src2, att_dst2, a_s2, a_d2, N);
  conv2_agg_wave<<<(N + 3) / 4, 256, 0, stream>>>(h2b, a_s2, a_d2, indptr2, nbr2, b2, x3, N);

  // output projection (rows Nc..N) -> d_out f32
  gemm_mfma_bt<false, true, false, false><<<dim3(1, (Ncol + 127) / 128), 256, 0, stream>>>(
      x3 + (size_t)Nc * 256, Woutb, b_out, (float*)d_out, Ncol, 256, 128, 256);
}

// Round 6
// 432.871 us; speedup vs baseline: 1.1491x; 1.0747x over previous
//
#include <hip/hip_runtime.h>

// ---------------------------------------------------------------------------
// GAT 2-layer forward on MI355X. Round 6:
//  - alpha (softmax weights) computed by thread-per-dst scalar kernels and
//    stored NORMALIZED in CSR slot order: aggregation becomes a pure weighted
//    gather (no cross-lane softmax, no online rescale).
//  - agg kernels: wave-per-dst, lane owns 4 channels -> each 512B row read
//    exactly once per wave; alpha broadcast via ds_read_b128.
//  - att_vec1 fused into prep; att_dots for conv2 fused into the conv2-GEMM
//    epilogue (tile rows are complete there).
//  - conv2 agg / alpha2 / x3 restricted to column nodes (rows Nc..N).
// ---------------------------------------------------------------------------

#define NEG_SLOPE 0.2f

typedef __attribute__((ext_vector_type(8))) short bf16x8;
typedef __attribute__((ext_vector_type(4))) float f32x4;

__device__ __forceinline__ float bf2f(unsigned short u) {
  return __uint_as_float(((unsigned)u) << 16);
}
__device__ __forceinline__ unsigned short f2bf(float f) {
  unsigned u = __float_as_uint(f);
  u += 0x7fffu + ((u >> 16) & 1u);   // round-to-nearest-even
  return (unsigned short)(u >> 16);
}

__device__ __forceinline__ void async_copy16(const void* g, void* l) {
  __builtin_amdgcn_global_load_lds(
      (const __attribute__((address_space(1))) unsigned int*)g,
      (__attribute__((address_space(3))) unsigned int*)l, 16, 0, 0);
}

// ---------------------------------------------------------------------------
// prep: fold W_node/W_col halves, convert MFMA operands to bf16, and compute
// v_s1/v_d1 = att1 @ W1 (per-head 256-dots) as an extra index range.
__global__ void prep(const float* __restrict__ Wn, const float* __restrict__ Wc,
                     const float* __restrict__ W1, const float* __restrict__ W2,
                     const float* __restrict__ Wout,
                     const float* __restrict__ cons, const float* __restrict__ cols,
                     const float* __restrict__ att_s1, const float* __restrict__ att_d1,
                     unsigned short* __restrict__ Wn_b, unsigned short* __restrict__ Wc_b,
                     unsigned short* __restrict__ W1b, unsigned short* __restrict__ W2b,
                     unsigned short* __restrict__ Woutb,
                     unsigned short* __restrict__ consb, unsigned short* __restrict__ colsb,
                     float* __restrict__ v_s1, float* __restrict__ v_d1,
                     int n_cons, int n_cols) {
  const int S0 = 256 * 64;
  const int S1 = 256 * 128;
  const int S2 = 2048 * 256;
  const int S3 = 256 * 2048;
  const int S4 = 128 * 256;
  const int S5 = 2048;                 // v1 (h,k) items
  int total = S0 + S1 + S2 + S3 + S4 + n_cons + n_cols + S5;
  for (int idx = blockIdx.x * 256 + threadIdx.x; idx < total; idx += gridDim.x * 256) {
    int i = idx;
    if (i < S0) { int o = i >> 6, j = i & 63;
      Wn_b[i] = f2bf(Wn[o * 128 + j] + Wn[o * 128 + 64 + j]); continue; }
    i -= S0;
    if (i < S1) { int o = i >> 7, j = i & 127;
      Wc_b[i] = f2bf(Wc[o * 256 + j] + Wc[o * 256 + 128 + j]); continue; }
    i -= S1;
    if (i < S2) { W1b[i] = f2bf(W1[i]); continue; }
    i -= S2;
    if (i < S3) { W2b[i] = f2bf(W2[i]); continue; }
    i -= S3;
    if (i < S4) { Woutb[i] = f2bf(Wout[i]); continue; }
    i -= S4;
    if (i < n_cons) { consb[i] = f2bf(cons[i]); continue; }
    i -= n_cons;
    if (i < n_cols) { colsb[i] = f2bf(cols[i]); continue; }
    i -= n_cols;
    { // v1: i in [0,2048), h = i>>8, k = i&255
      int h = i >> 8, k = i & 255;
      const float* Wrow = W1 + (size_t)h * 256 * 256 + k;
      const float* as = att_s1 + h * 256;
      const float* ad = att_d1 + h * 256;
      float s = 0.f, d = 0.f;
      for (int c = 0; c < 256; ++c) {
        float w = Wrow[(size_t)c * 256];
        s += as[c] * w;
        d += ad[c] * w;
      }
      v_s1[i] = s; v_d1[i] = d;
    }
  }
}

// ---------------------------------------------------------------------------
// a_s1[n,h] = xb[n,:] . v_s[h,:]  (thread per node; v in LDS, broadcast reads)
__global__ __launch_bounds__(256) void a1_dots(const unsigned short* __restrict__ xb,
                                               const float* __restrict__ v_s,
                                               const float* __restrict__ v_d,
                                               float* __restrict__ a_s,
                                               float* __restrict__ a_d, int N) {
  __shared__ float vs[2048], vd[2048];
  for (int i = threadIdx.x; i < 2048; i += 256) { vs[i] = v_s[i]; vd[i] = v_d[i]; }
  __syncthreads();
  int n = blockIdx.x * 256 + threadIdx.x;
  if (n >= N) return;
  const unsigned short* row = xb + (size_t)n * 256;
  float s[8] = {}, d[8] = {};
  for (int c = 0; c < 256; c += 8) {
    bf16x8 xv = *(const bf16x8*)(row + c);
    float xf[8];
#pragma unroll
    for (int i = 0; i < 8; ++i) xf[i] = bf2f(((const unsigned short*)&xv)[i]);
#pragma unroll
    for (int h = 0; h < 8; ++h)
#pragma unroll
      for (int i = 0; i < 8; ++i) {
        s[h] += xf[i] * vs[h * 256 + c + i];
        d[h] += xf[i] * vd[h * 256 + c + i];
      }
  }
#pragma unroll
  for (int h = 0; h < 8; ++h) { a_s[n * 8 + h] = s[h]; a_d[n * 8 + h] = d[h]; }
}

// ---------------------------------------------------------------------------
// bf16 MFMA GEMM, B^T layout: C[m,n] = sum_k A[m, koff+k] * W[n,k] (+bias,relu).
// BDIAG: koff = (n0/256)*256 with A row-stride lda (block-diagonal projection).
template <bool C_BF16, bool BIAS, bool RELU, bool BDIAG>
__global__ __launch_bounds__(256) void gemm_mfma_bt(const unsigned short* __restrict__ A,
                                                    const unsigned short* __restrict__ W,
                                                    const float* __restrict__ bias,
                                                    void* __restrict__ Cv,
                                                    int M, int K, int Nout, int lda) {
  __shared__ short sA[128 * 64];
  __shared__ short sB[128 * 64];
  float* Cf = (float*)Cv;
  unsigned short* Cb = (unsigned short*)Cv;

  const int tid = threadIdx.x;
  const int lane = tid & 63, w = tid >> 6;
  const int m0 = blockIdx.y * 128, n0 = blockIdx.x * 128;
  const int koff = BDIAG ? (n0 >> 8) << 8 : 0;
  const int wm = (w >> 1) * 64, wn = (w & 1) * 64;
  const int fr = lane & 15;
  const int quad = lane >> 4;

  f32x4 acc[4][4];
#pragma unroll
  for (int i = 0; i < 4; ++i)
#pragma unroll
    for (int j = 0; j < 4; ++j) acc[i][j] = (f32x4){0.f, 0.f, 0.f, 0.f};

  for (int k0 = 0; k0 < K; k0 += 64) {
#pragma unroll
    for (int i = 0; i < 4; ++i) {
      int c = i * 256 + tid;
      int row = c >> 3, kc = c & 7;
      int grow = m0 + row;
      if (grow >= M) grow = M - 1;
      async_copy16(A + (size_t)grow * lda + koff + k0 + kc * 8, &sA[(i * 256 + w * 64) * 8]);
    }
#pragma unroll
    for (int i = 0; i < 4; ++i) {
      int c = i * 256 + tid;
      int row = c >> 3, kc = c & 7;
      async_copy16(W + (size_t)(n0 + row) * K + k0 + kc * 8, &sB[(i * 256 + w * 64) * 8]);
    }
    __syncthreads();

#pragma unroll
    for (int ks = 0; ks < 2; ++ks) {
      bf16x8 af[4], bfr[4];
#pragma unroll
      for (int mi = 0; mi < 4; ++mi)
        af[mi] = *(const bf16x8*)&sA[(wm + mi * 16 + fr) * 64 + ks * 32 + quad * 8];
#pragma unroll
      for (int ni = 0; ni < 4; ++ni)
        bfr[ni] = *(const bf16x8*)&sB[(wn + ni * 16 + fr) * 64 + ks * 32 + quad * 8];
#pragma unroll
      for (int mi = 0; mi < 4; ++mi)
#pragma unroll
        for (int ni = 0; ni < 4; ++ni)
          acc[mi][ni] = __builtin_amdgcn_mfma_f32_16x16x32_bf16(
              af[mi], bfr[ni], acc[mi][ni], 0, 0, 0);
    }
    __syncthreads();
  }

#pragma unroll
  for (int mi = 0; mi < 4; ++mi) {
#pragma unroll
    for (int ni = 0; ni < 4; ++ni) {
      int col = n0 + wn + ni * 16 + fr;
      float bv = BIAS ? bias[col] : 0.f;
      f32x4 v = acc[mi][ni];
#pragma unroll
      for (int r = 0; r < 4; ++r) {
        int row = m0 + wm + mi * 16 + quad * 4 + r;
        if (row < M) {
          float x = v[r] + bv;
          if (RELU) x = fmaxf(x, 0.f);
          size_t o = (size_t)row * Nout + col;
          if (C_BF16) Cb[o] = f2bf(x); else Cf[o] = x;
        }
      }
    }
  }
}

// ---------------------------------------------------------------------------
// conv2 projection GEMM: h2[M,256] = A[M,2048] * W[256,2048]^T, bf16 out,
// PLUS fused attention dots: a_s2[m] = h2[m,:].att_s, a_d2 likewise.
// Tile 32x256 (full Nout per block -> rows complete); grid = M/32 blocks.
__global__ __launch_bounds__(256) void gemm_mfma_k2048(const unsigned short* __restrict__ A,
                                                       const unsigned short* __restrict__ W,
                                                       unsigned short* __restrict__ C,
                                                       const float* __restrict__ att_s,
                                                       const float* __restrict__ att_d,
                                                       float* __restrict__ a_s,
                                                       float* __restrict__ a_d,
                                                       int M, int K) {
  __shared__ short sA[32 * 64];
  __shared__ short sB[256 * 64];
  const int tid = threadIdx.x;
  const int lane = tid & 63, w = tid >> 6;
  const int m0 = blockIdx.x * 32;
  const int fr = lane & 15, quad = lane >> 4;

  f32x4 acc[2][4];
#pragma unroll
  for (int i = 0; i < 2; ++i)
#pragma unroll
    for (int j = 0; j < 4; ++j) acc[i][j] = (f32x4){0.f, 0.f, 0.f, 0.f};

  for (int k0 = 0; k0 < K; k0 += 64) {
    {
      int row = tid >> 3, kc = tid & 7;
      int grow = m0 + row;
      if (grow >= M) grow = M - 1;
      async_copy16(A + (size_t)grow * K + k0 + kc * 8, &sA[(w * 64) * 8]);
    }
#pragma unroll
    for (int i = 0; i < 8; ++i) {
      int c = i * 256 + tid;
      int row = c >> 3, kc = c & 7;
      async_copy16(W + (size_t)row * K + k0 + kc * 8, &sB[(i * 256 + w * 64) * 8]);
    }
    __syncthreads();

#pragma unroll
    for (int ks = 0; ks < 2; ++ks) {
      bf16x8 af[2], bfr[4];
#pragma unroll
      for (int mi = 0; mi < 2; ++mi)
        af[mi] = *(const bf16x8*)&sA[(mi * 16 + fr) * 64 + ks * 32 + quad * 8];
#pragma unroll
      for (int ni = 0; ni < 4; ++ni)
        bfr[ni] = *(const bf16x8*)&sB[(w * 64 + ni * 16 + fr) * 64 + ks * 32 + quad * 8];
#pragma unroll
      for (int mi = 0; mi < 2; ++mi)
#pragma unroll
        for (int ni = 0; ni < 4; ++ni)
          acc[mi][ni] = __builtin_amdgcn_mfma_f32_16x16x32_bf16(
              af[mi], bfr[ni], acc[mi][ni], 0, 0, 0);
    }
    __syncthreads();
  }

  // epilogue: write global bf16 + stage tile in LDS for fused att dots
  unsigned short* hsh = (unsigned short*)sB;   // 32x256 u16 = 16KB (sB is 32KB)
#pragma unroll
  for (int mi = 0; mi < 2; ++mi)
#pragma unroll
    for (int ni = 0; ni < 4; ++ni) {
      int col = w * 64 + ni * 16 + fr;
      f32x4 v = acc[mi][ni];
#pragma unroll
      for (int r = 0; r < 4; ++r) {
        int rl = mi * 16 + quad * 4 + r;
        int row = m0 + rl;
        unsigned short hv = f2bf(v[r]);
        hsh[rl * 256 + col] = hv;
        if (row < M) C[(size_t)row * 256 + col] = hv;
      }
    }
  __syncthreads();

  // dots: 8 threads per row, 32 cols each, shfl-reduce within the 8-lane group
  int r = tid >> 3;
  int cbase = (tid & 7) * 32;
  float s = 0.f, d = 0.f;
#pragma unroll 8
  for (int i = 0; i < 32; ++i) {
    int c = cbase + i;
    float hv = bf2f(hsh[r * 256 + c]);
    s += hv * att_s[c];
    d += hv * att_d[c];
  }
#pragma unroll
  for (int off = 4; off; off >>= 1) {
    s += __shfl_down(s, off);
    d += __shfl_down(d, off);
  }
  if ((tid & 7) == 0 && m0 + r < M) {
    a_s[m0 + r] = s;
    a_d[m0 + r] = d;
  }
}

// ---------------------------------------------------------------------------
// Edge materialization + degree counts (fused). int64/int32 auto-detect.
__global__ void build_count(const void* __restrict__ edges_raw, int E, int N,
                            int* __restrict__ esrc, int* __restrict__ edst,
                            int* __restrict__ cnt1, int* __restrict__ cnt2, int E1) {
  const long long* p64 = (const long long*)edges_raw;
  const int* p32 = (const int*)edges_raw;
  bool is64 = true;
#pragma unroll
  for (int i = 0; i < 8; ++i) {
    long long v = p64[i];
    if (v < 0 || v >= N) is64 = false;
  }
  int idx = blockIdx.x * 256 + threadIdx.x;
  if (idx >= E1) return;
  int s, d;
  if (idx < E) {
    if (is64) { s = (int)p64[idx]; d = (int)p64[E + idx]; }
    else      { s = p32[idx];      d = p32[E + idx]; }
  } else {
    s = d = idx - E;
  }
  esrc[idx] = s;
  edst[idx] = d;
  atomicAdd(&cnt1[d], 1);
  atomicAdd(&cnt2[s], 1);
}

// ---------------------------------------------------------------------------
// Shuffle-based single-block scan: 3 barriers per 1024-chunk.
__device__ __forceinline__ void scan_one(const int* __restrict__ cnt,
                                         int* __restrict__ indptr,
                                         int* __restrict__ cur, int N, int* buf) {
  int t = threadIdx.x, lane = t & 63, w = t >> 6;
  int running = 0;
  for (int base = 0; base < N; base += 1024) {
    int v = (base + t < N) ? cnt[base + t] : 0;
    int incl = v;
#pragma unroll
    for (int off = 1; off < 64; off <<= 1) {
      int y = __shfl_up(incl, off);
      if (lane >= off) incl += y;
    }
    if (lane == 63) buf[w] = incl;
    __syncthreads();
    if (t < 16) {
      int x = buf[t];
#pragma unroll
      for (int off = 1; off < 16; off <<= 1) {
        int y = __shfl_up(x, off);
        if (t >= off) x += y;
      }
      buf[t] = x;
    }
    __syncthreads();
    int woff = w ? buf[w - 1] : 0;
    int tot = buf[15];
    if (base + t < N) {
      int excl = running + woff + incl - v;
      indptr[base + t] = excl;
      cur[base + t] = excl;
    }
    running += tot;
    __syncthreads();
  }
  if (t == 0) indptr[N] = running;
  __syncthreads();
}

__global__ __launch_bounds__(1024) void scan2_kernel(const int* cnt1, int* indptr1, int* cur1,
                                                     const int* cnt2, int* indptr2, int* cur2,
                                                     int N) {
  __shared__ int buf[16];
  scan_one(cnt1, indptr1, cur1, N, buf);
  scan_one(cnt2, indptr2, cur2, N, buf);
}

// scatter neighbor node-ids directly.
__global__ void scatter_edges(const int* __restrict__ esrc, const int* __restrict__ edst,
                              int* __restrict__ cur1, int* __restrict__ cur2,
                              int* __restrict__ nbr1, int* __restrict__ nbr2, int E1) {
  int e = blockIdx.x * 256 + threadIdx.x;
  if (e >= E1) return;
  int s = esrc[e], d = edst[e];
  int p1 = atomicAdd(&cur1[d], 1);
  nbr1[p1] = s;
  int p2 = atomicAdd(&cur2[s], 1);
  nbr2[p2] = d;
}

// ---------------------------------------------------------------------------
// alpha1: thread-per-dst scalar online softmax (8 heads); writes NORMALIZED
// alpha to CSR slots [slot*8+h].
__global__ __launch_bounds__(256) void alpha1_kernel(const float* __restrict__ a_s,
                                                     const float* __restrict__ a_d,
                                                     const int* __restrict__ indptr,
                                                     const int* __restrict__ nbr,
                                                     float* __restrict__ alpha, int N) {
  int n = blockIdx.x * 256 + threadIdx.x;
  if (n >= N) return;
  int start = indptr[n], end = indptr[n + 1];
  float ad[8];
  *(float4*)&ad[0] = *(const float4*)&a_d[n * 8];
  *(float4*)&ad[4] = *(const float4*)&a_d[n * 8 + 4];
  float m[8], ssum[8];
#pragma unroll
  for (int h = 0; h < 8; ++h) { m[h] = -1e30f; ssum[h] = 0.f; }
  for (int p = start; p < end; ++p) {
    int s = nbr[p];
    float as[8];
    *(float4*)&as[0] = *(const float4*)&a_s[s * 8];
    *(float4*)&as[4] = *(const float4*)&a_s[s * 8 + 4];
#pragma unroll
    for (int h = 0; h < 8; ++h) {
      float e = as[h] + ad[h];
      e = e > 0.f ? e : NEG_SLOPE * e;
      float nm = fmaxf(m[h], e);
      ssum[h] = ssum[h] * __expf(m[h] - nm) + __expf(e - nm);
      m[h] = nm;
    }
  }
  float inv[8];
#pragma unroll
  for (int h = 0; h < 8; ++h) inv[h] = 1.f / (ssum[h] + 1e-16f);
  for (int p = start; p < end; ++p) {
    int s = nbr[p];
    float as[8];
    *(float4*)&as[0] = *(const float4*)&a_s[s * 8];
    *(float4*)&as[4] = *(const float4*)&a_s[s * 8 + 4];
    float av[8];
#pragma unroll
    for (int h = 0; h < 8; ++h) {
      float e = as[h] + ad[h];
      e = e > 0.f ? e : NEG_SLOPE * e;
      av[h] = __expf(e - m[h]) * inv[h];
    }
    *(float4*)&alpha[(size_t)p * 8] = *(const float4*)&av[0];
    *(float4*)&alpha[(size_t)p * 8 + 4] = *(const float4*)&av[4];
  }
}

// alpha2: same, 1 head, only for dst in [Nc, N).
__global__ __launch_bounds__(256) void alpha2_kernel(const float* __restrict__ a_s,
                                                     const float* __restrict__ a_d,
                                                     const int* __restrict__ indptr,
                                                     const int* __restrict__ nbr,
                                                     float* __restrict__ alpha,
                                                     int Nc, int Ncol) {
  int i = blockIdx.x * 256 + threadIdx.x;
  if (i >= Ncol) return;
  int n = Nc + i;
  int start = indptr[n], end = indptr[n + 1];
  float ad = a_d[n];
  float m = -1e30f, ssum = 0.f;
  for (int p = start; p < end; ++p) {
    float e = a_s[nbr[p]] + ad;
    e = e > 0.f ? e : NEG_SLOPE * e;
    float nm = fmaxf(m, e);
    ssum = ssum * __expf(m - nm) + __expf(e - nm);
    m = nm;
  }
  float inv = 1.f / (ssum + 1e-16f);
  for (int p = start; p < end; ++p) {
    float e = a_s[nbr[p]] + ad;
    e = e > 0.f ? e : NEG_SLOPE * e;
    alpha[p] = __expf(e - m) * inv;
  }
}

// ---------------------------------------------------------------------------
// conv1 aggregation, lean: wave-per-dst (4/block), alphas precomputed.
// Lane owns channels [4*lane, 4*lane+4): each 512B source row read once/wave.
// acc[h][i]: 8 heads x 4 channels.
__global__ __launch_bounds__(256) void agg1_kernel(const unsigned short* __restrict__ xb,
                                                   const float* __restrict__ alpha,
                                                   const int* __restrict__ indptr,
                                                   const int* __restrict__ nbr,
                                                   unsigned short* __restrict__ agg,
                                                   int N) {
  __shared__ float al_sh[4][64 * 8];
  const int w = threadIdx.x >> 6, lane = threadIdx.x & 63;
  const int dst = blockIdx.x * 4 + w;
  if (dst >= N) return;
  const int start = indptr[dst];
  const int deg = indptr[dst + 1] - start;
  const int c0 = lane * 4;

  float acc[8][4];
#pragma unroll
  for (int h = 0; h < 8; ++h)
#pragma unroll
    for (int i = 0; i < 4; ++i) acc[h][i] = 0.f;

  for (int base = 0; base < deg; base += 64) {
    int cnt = min(64, deg - base);
    int s = 0;
    if (lane < cnt) {
      int slot = start + base + lane;
      s = nbr[slot];
      f32x4 a0 = *(const f32x4*)&alpha[(size_t)slot * 8];
      f32x4 a1 = *(const f32x4*)&alpha[(size_t)slot * 8 + 4];
      *(f32x4*)&al_sh[w][lane * 8] = a0;
      *(f32x4*)&al_sh[w][lane * 8 + 4] = a1;
    }
    __builtin_amdgcn_wave_barrier();
    for (int j = 0; j < cnt; ++j) {
      int sj = __shfl(s, j);
      f32x4 alo = *(const f32x4*)&al_sh[w][j * 8];
      f32x4 ahi = *(const f32x4*)&al_sh[w][j * 8 + 4];
      ushort4 xv = *(const ushort4*)(xb + (size_t)sj * 256 + c0);
      float x0 = bf2f(xv.x), x1 = bf2f(xv.y), x2 = bf2f(xv.z), x3 = bf2f(xv.w);
#pragma unroll
      for (int h = 0; h < 4; ++h) {
        acc[h][0] += alo[h] * x0; acc[h][1] += alo[h] * x1;
        acc[h][2] += alo[h] * x2; acc[h][3] += alo[h] * x3;
      }
#pragma unroll
      for (int h = 0; h < 4; ++h) {
        acc[h + 4][0] += ahi[h] * x0; acc[h + 4][1] += ahi[h] * x1;
        acc[h + 4][2] += ahi[h] * x2; acc[h + 4][3] += ahi[h] * x3;
      }
    }
    __builtin_amdgcn_wave_barrier();
  }

  unsigned short* op = agg + (size_t)dst * 2048;
#pragma unroll
  for (int h = 0; h < 8; ++h) {
    unsigned short ov[4];
#pragma unroll
    for (int i = 0; i < 4; ++i) ov[i] = f2bf(acc[h][i]);
    *((ushort4*)(op + h * 256 + c0)) = *((const ushort4*)ov);
  }
}

// ---------------------------------------------------------------------------
// conv2 aggregation, lean: wave-per-dst (4/block), dst in [Nc,N) only.
// Lane owns channels [4*lane, +4). x3 stores only Ncol rows.
__global__ __launch_bounds__(256) void agg2_kernel(const unsigned short* __restrict__ h2,
                                                   const float* __restrict__ alpha,
                                                   const int* __restrict__ indptr,
                                                   const int* __restrict__ nbr,
                                                   const float* __restrict__ b2,
                                                   unsigned short* __restrict__ x3,
                                                   int Nc, int Ncol) {
  const int w = threadIdx.x >> 6, lane = threadIdx.x & 63;
  const int i0 = blockIdx.x * 4 + w;
  if (i0 >= Ncol) return;
  const int dst = Nc + i0;
  const int start = indptr[dst];
  const int deg = indptr[dst + 1] - start;
  const int c0 = lane * 4;
  float acc[4] = {0.f, 0.f, 0.f, 0.f};

  for (int base = 0; base < deg; base += 64) {
    int cnt = min(64, deg - base);
    int s = 0; float a = 0.f;
    if (lane < cnt) {
      int slot = start + base + lane;
      s = nbr[slot];
      a = alpha[slot];
    }
    for (int j = 0; j < cnt; ++j) {
      int sj = __shfl(s, j);
      float al = __shfl(a, j);
      ushort4 hv = *(const ushort4*)(h2 + (size_t)sj * 256 + c0);
      acc[0] += al * bf2f(hv.x);
      acc[1] += al * bf2f(hv.y);
      acc[2] += al * bf2f(hv.z);
      acc[3] += al * bf2f(hv.w);
    }
  }

  float4 bv = *(const float4*)&b2[c0];
  unsigned short ov[4];
  ov[0] = f2bf(fmaxf(acc[0] + bv.x, 0.f));
  ov[1] = f2bf(fmaxf(acc[1] + bv.y, 0.f));
  ov[2] = f2bf(fmaxf(acc[2] + bv.z, 0.f));
  ov[3] = f2bf(fmaxf(acc[3] + bv.w, 0.f));
  *((ushort4*)(x3 + (size_t)i0 * 256 + c0)) = *((const ushort4*)ov);
}

// ---------------------------------------------------------------------------
extern "C" void kernel_launch(void* const* d_in, const int* in_sizes, int n_in,
                              void* d_out, int out_size, void* d_ws, size_t ws_size,
                              hipStream_t stream) {
  (void)n_in; (void)out_size; (void)ws_size;
  const float* constraints = (const float*)d_in[0];
  const float* columns     = (const float*)d_in[1];
  const void*  edges       = d_in[2];
  const float* W_node = (const float*)d_in[3];
  const float* b_node = (const float*)d_in[4];
  const float* W_col  = (const float*)d_in[5];
  const float* b_col  = (const float*)d_in[6];
  const float* W1       = (const float*)d_in[7];
  const float* att_src1 = (const float*)d_in[8];
  const float* att_dst1 = (const float*)d_in[9];
  const float* b1       = (const float*)d_in[10];
  const float* W2       = (const float*)d_in[11];
  const float* att_src2 = (const float*)d_in[12];
  const float* att_dst2 = (const float*)d_in[13];
  const float* b2       = (const float*)d_in[14];
  const float* W_out    = (const float*)d_in[15];
  const float* b_out    = (const float*)d_in[16];

  const int Nc   = in_sizes[0] / 64;
  const int Ncol = in_sizes[1] / 128;
  const int E    = in_sizes[2] / 2;
  const int N    = Nc + Ncol;
  const int E1   = E + N;

  char* p = (char*)d_ws;
  size_t off = 0;
  auto alloc = [&](size_t nbytes) -> void* {
    void* r = p + off;
    off = (off + nbytes + 255) & ~(size_t)255;
    return r;
  };
  unsigned short* Wn_b  = (unsigned short*)alloc(2ull * 256 * 64);
  unsigned short* Wc_b  = (unsigned short*)alloc(2ull * 256 * 128);
  unsigned short* W1b   = (unsigned short*)alloc(2ull * 2048 * 256);
  unsigned short* W2b   = (unsigned short*)alloc(2ull * 256 * 2048);
  unsigned short* Woutb = (unsigned short*)alloc(2ull * 128 * 256);
  unsigned short* consb = (unsigned short*)alloc(2ull * (size_t)Nc * 64);
  unsigned short* colsb = (unsigned short*)alloc(2ull * (size_t)Ncol * 128);
  unsigned short* xb    = (unsigned short*)alloc(2ull * (size_t)N * 256);
  float* v_s1 = (float*)alloc(sizeof(float) * 8 * 256);
  float* v_d1 = (float*)alloc(sizeof(float) * 8 * 256);
  float* a_s1 = (float*)alloc(sizeof(float) * (size_t)N * 8);
  float* a_d1 = (float*)alloc(sizeof(float) * (size_t)N * 8);
  int* esrc = (int*)alloc(4ull * E1);
  int* edst = (int*)alloc(4ull * E1);
  int* cnt1 = (int*)alloc(4ull * 2 * N);
  int* cnt2 = cnt1 + N;
  int* indptr1 = (int*)alloc(4ull * (N + 1));
  int* cur1    = (int*)alloc(4ull * N);
  int* indptr2 = (int*)alloc(4ull * (N + 1));
  int* cur2    = (int*)alloc(4ull * N);
  int* nbr1 = (int*)alloc(4ull * E1);
  int* nbr2 = (int*)alloc(4ull * E1);
  float* alpha1 = (float*)alloc(sizeof(float) * 8ull * E1);
  float* alpha2 = (float*)alloc(sizeof(float) * (size_t)E1);
  unsigned short* agg = (unsigned short*)alloc(2ull * (size_t)N * 2048);
  unsigned short* x2  = (unsigned short*)alloc(2ull * (size_t)N * 2048);
  unsigned short* h2b = (unsigned short*)alloc(2ull * (size_t)N * 256);
  float* a_s2 = (float*)alloc(sizeof(float) * (size_t)N);
  float* a_d2 = (float*)alloc(sizeof(float) * (size_t)N);
  unsigned short* x3 = (unsigned short*)alloc(2ull * (size_t)Ncol * 256);

  hipMemsetAsync(cnt1, 0, 4ull * 2 * N, stream);
  prep<<<1024, 256, 0, stream>>>(W_node, W_col, W1, W2, W_out, constraints, columns,
                                 att_src1, att_dst1,
                                 Wn_b, Wc_b, W1b, W2b, Woutb, consb, colsb,
                                 v_s1, v_d1, Nc * 64, Ncol * 128);

  // encoder (MFMA, bf16 -> xb)
  gemm_mfma_bt<true, true, true, false><<<dim3(2, (Nc + 127) / 128), 256, 0, stream>>>(
      consb, Wn_b, b_node, xb, Nc, 64, 256, 64);
  gemm_mfma_bt<true, true, true, false><<<dim3(2, (Ncol + 127) / 128), 256, 0, stream>>>(
      colsb, Wc_b, b_col, xb + (size_t)Nc * 256, Ncol, 128, 256, 128);

  // attention logits for conv1
  a1_dots<<<(N + 255) / 256, 256, 0, stream>>>(xb, v_s1, v_d1, a_s1, a_d1, N);

  // graph CSR (both directions, neighbor ids stored directly)
  build_count<<<(E1 + 255) / 256, 256, 0, stream>>>(edges, E, N, esrc, edst, cnt1, cnt2, E1);
  scan2_kernel<<<1, 1024, 0, stream>>>(cnt1, indptr1, cur1, cnt2, indptr2, cur2, N);
  scatter_edges<<<(E1 + 255) / 256, 256, 0, stream>>>(esrc, edst, cur1, cur2, nbr1, nbr2, E1);

  // conv1: alphas (thread-per-dst), lean aggregation, block-diag projection
  alpha1_kernel<<<(N + 255) / 256, 256, 0, stream>>>(a_s1, a_d1, indptr1, nbr1, alpha1, N);
  agg1_kernel<<<(N + 3) / 4, 256, 0, stream>>>(xb, alpha1, indptr1, nbr1, agg, N);
  gemm_mfma_bt<true, true, true, true><<<dim3(16, (N + 127) / 128), 256, 0, stream>>>(
      agg, W1b, b1, x2, N, 256, 2048, 2048);

  // conv2: projection with fused att dots, alphas, lean aggregation (col rows)
  gemm_mfma_k2048<<<(N + 31) / 32, 256, 0, stream>>>(
      x2, W2b, h2b, att_src2, att_dst2, a_s2, a_d2, N, 2048);
  alpha2_kernel<<<(Ncol + 255) / 256, 256, 0, stream>>>(a_s2, a_d2, indptr2, nbr2, alpha2,
                                                        Nc, Ncol);
  agg2_kernel<<<(Ncol + 3) / 4, 256, 0, stream>>>(h2b, alpha2, indptr2, nbr2, b2, x3,
                                                  Nc, Ncol);

  // output projection -> d_out f32
  gemm_mfma_bt<false, true, false, false><<<dim3(1, (Ncol + 127) / 128), 256, 0, stream>>>(
      x3, Woutb, b_out, (float*)d_out, Ncol, 256, 128, 256);
}